// Round 2
// baseline (1012.967 us; speedup 1.0000x reference)
//
#include <hip/hip_runtime.h>
#include <math.h>

// Problem constants (from reference)
constexpr int B_SZ = 16384;
constexpr long long CELLS = 4194304;   // 16384*256 cells, 2 anchor slots each
constexpr int CLS_CELLS = 8192;        // logits[:batch_size] -> first 8192 cells get cls loss
constexpr float NOOBJ_SCALE = 0.5f;
constexpr float COORD_SCALE = 5.0f;

constexpr int TPB = 256;               // threads per block == cells per block
constexpr int PRED_PITCH = 13;         // 12 floats + 1 pad (odd stride -> 2-way LDS = free)
constexpr int TGT_PITCH  = 9;          // 8 floats + 1 pad
constexpr int NBLOCKS = (int)(CELLS / TPB);   // 16384 partial slots in d_ws
constexpr unsigned FLAG_MAGIC = 0x5AD0BEEFu;  // != 0xAAAAAAAA poison, != 0

// Native clang vector so __builtin_nontemporal_load is applicable.
typedef float f4 __attribute__((ext_vector_type(4)));

// Per-(cell,slot) loss contribution.
// pred slot layout: offset=p0, dur=p1, conf=p2, cls=p3..p5  (slot1: +6)
// target slot layout: conf, cls, offset, dur                (slot1: +4)
__device__ __forceinline__ float slot_loss(float pc, float l0, float l1, float l2,
                                           float po, float pd,
                                           float tc, float tcls, float to, float td,
                                           bool do_cls) {
    float d = tc - pc;
    bool obj = (tc == 1.0f);
    float w = obj ? 1.0f : ((tc == 0.0f) ? NOOBJ_SCALE : 0.0f);
    float r = w * d * d;

    if (obj) {
        float doff = to - po;
        r += COORD_SCALE * doff * doff;
        float dd = sqrtf(td) - sqrtf(pd);
        r += COORD_SCALE * dd * dd;
    }
    if (do_cls) {
        float x0, x1, x2;
        int idx;
        if (obj) { x0 = l0; x1 = l1; x2 = l2; idx = (int)tcls; }
        else     { x0 = 0.f; x1 = 0.f; x2 = 0.f; idx = 0; }
        float m = fmaxf(x0, fmaxf(x1, x2));
        float lse = logf(expf(x0 - m) + expf(x1 - m) + expf(x2 - m)) + m;
        float li = (idx == 0) ? x0 : ((idx == 1) ? x1 : x2);
        r += lse - li;   // cross-entropy = logsumexp - logit[target]
    }
    return r;
}

// Single fused dispatch: every block computes its tile's partial, release-stores
// it with a MAGIC flag (agent scope -> cross-XCD coherent); the LAST-dispatched
// block (in-order CP => scheduled last, near-zero spin) polls all flags and does
// the final 256-thread reduction, replicating the old finalize kernel's exact
// summation order (bit-identical result).
__global__ __launch_bounds__(256) void ensemble_loss_kernel(
        const float* __restrict__ pred,
        const float* __restrict__ target,
        double* __restrict__ partials,
        unsigned* __restrict__ flags,
        float* __restrict__ out) {
    // Padded LDS tiles: 256*13*4 = 13312 B + 256*9*4 = 9216 B = ~22.5 KB
    __shared__ float spred[TPB * PRED_PITCH];
    __shared__ float star[TPB * TGT_PITCH];
    __shared__ float wsumf[4];
    __shared__ double wsumd[4];

    const int tid = threadIdx.x;
    const long long cell0 = (long long)blockIdx.x * TPB;

    // ---- stage pred: 768 float4/block, lane-contiguous (coalesced) ----
    // Streaming single-use data: nontemporal (no reuse; poison fill evicts caches anyway).
    const f4* __restrict__ pbase = (const f4*)pred + cell0 * 3;
    #pragma unroll
    for (int r = 0; r < 3; ++r) {
        int g = r * TPB + tid;              // 0..767
        f4 v = __builtin_nontemporal_load(pbase + g);
        int cell = g / 3;                   // magic-mul div
        int sub  = g - cell * 3;
        int a = cell * PRED_PITCH + 4 * sub;
        spred[a + 0] = v.x; spred[a + 1] = v.y;
        spred[a + 2] = v.z; spred[a + 3] = v.w;
    }
    // ---- stage target: 512 float4/block, lane-contiguous ----
    const f4* __restrict__ tbase = (const f4*)target + cell0 * 2;
    #pragma unroll
    for (int r = 0; r < 2; ++r) {
        int g = r * TPB + tid;              // 0..511
        f4 v = __builtin_nontemporal_load(tbase + g);
        int cell = g >> 1;
        int sub  = g & 1;
        int a = cell * TGT_PITCH + 4 * sub;
        star[a + 0] = v.x; star[a + 1] = v.y;
        star[a + 2] = v.z; star[a + 3] = v.w;
    }
    __syncthreads();

    // ---- compute: thread t handles cell (cell0 + t) ----
    const float* P = &spred[tid * PRED_PITCH];
    const float* T = &star[tid * TGT_PITCH];
    const bool do_cls = (cell0 + tid) < CLS_CELLS;   // blocks 0..31 only (wave-uniform)

    float acc = 0.0f;
    acc += slot_loss(P[2], P[3], P[4], P[5], P[0], P[1],
                     T[0], T[1], T[2], T[3], do_cls);
    acc += slot_loss(P[8], P[9], P[10], P[11], P[6], P[7],
                     T[4], T[5], T[6], T[7], do_cls);

    // wave(64) shuffle reduction
    for (int off = 32; off > 0; off >>= 1)
        acc += __shfl_down(acc, off, 64);

    const int lane = tid & 63;
    const int wv = tid >> 6;
    if (lane == 0) wsumf[wv] = acc;
    __syncthreads();
    if (tid == 0) {
        float s = wsumf[0] + wsumf[1] + wsumf[2] + wsumf[3];
        // Agent-scope atomics: visible across non-coherent per-XCD L2s.
        __hip_atomic_store(&partials[blockIdx.x], (double)s,
                           __ATOMIC_RELAXED, __HIP_MEMORY_SCOPE_AGENT);
        __hip_atomic_store(&flags[blockIdx.x], FLAG_MAGIC,
                           __ATOMIC_RELEASE, __HIP_MEMORY_SCOPE_AGENT);
    }

    if (blockIdx.x != NBLOCKS - 1) return;

    // ---- fused finalize (last-dispatched block only) ----
    // Poll: thread t owns flags t, t+256, ... (coalesced). Robust to any ws
    // poison value (poison != MAGIC). Even if re-poison were ever skipped,
    // stale partials carry identical values (inputs constant per bench).
    for (;;) {
        int notdone = 0;
        for (int i = 0; i < NBLOCKS / TPB; ++i) {
            unsigned f = __hip_atomic_load(&flags[i * TPB + tid],
                                           __ATOMIC_RELAXED, __HIP_MEMORY_SCOPE_AGENT);
            notdone += (f != FLAG_MAGIC) ? 1 : 0;
        }
        if (__syncthreads_and(notdone == 0)) break;
        __builtin_amdgcn_s_sleep(2);    // brief backoff between poll passes
    }
    __threadfence();                    // acquire: order partial reads after flags

    // Same summation order as the old finalize kernel -> bit-identical output.
    double s = 0.0;
    #pragma unroll
    for (int i = 0; i < NBLOCKS / TPB; ++i)
        s += __hip_atomic_load(&partials[i * TPB + tid],
                               __ATOMIC_RELAXED, __HIP_MEMORY_SCOPE_AGENT);

    for (int off = 32; off > 0; off >>= 1)
        s += __shfl_down(s, off, 64);

    if (lane == 0) wsumd[wv] = s;
    __syncthreads();
    if (tid == 0) {
        double t = wsumd[0] + wsumd[1] + wsumd[2] + wsumd[3];
        out[0] = (float)(t * (1.0 / (double)B_SZ));
    }
}

extern "C" void kernel_launch(void* const* d_in, const int* in_sizes, int n_in,
                              void* d_out, int out_size, void* d_ws, size_t ws_size,
                              hipStream_t stream) {
    const float* pred   = (const float*)d_in[0];
    const float* target = (const float*)d_in[1];
    float* out = (float*)d_out;

    // ws layout: [0, 128 KB) partials (16384 doubles), [128 KB, 192 KB) flags.
    double*   partials = (double*)d_ws;
    unsigned* flags    = (unsigned*)((char*)d_ws + NBLOCKS * sizeof(double));

    // Single dispatch: no memset (all slots + flags written unconditionally),
    // finalize fused via last-block flag poll.
    ensemble_loss_kernel<<<NBLOCKS, TPB, 0, stream>>>(pred, target, partials, flags, out);
}

// Round 3
// 340.421 us; speedup vs baseline: 2.9756x; 2.9756x over previous
//
#include <hip/hip_runtime.h>
#include <math.h>

// Problem constants (from reference)
constexpr int B_SZ = 16384;
constexpr long long CELLS = 4194304;   // 16384*256 cells, 2 anchor slots each
constexpr int CLS_CELLS = 8192;        // logits[:batch_size] -> first 8192 cells get cls loss
constexpr float NOOBJ_SCALE = 0.5f;
constexpr float COORD_SCALE = 5.0f;

constexpr int TPB = 256;
constexpr int NBLOCKS = (int)(CELLS / TPB);   // 16384 partial slots in d_ws (128 KB)

// Native clang vector so __builtin_nontemporal_load is applicable.
typedef float f4 __attribute__((ext_vector_type(4)));

// Per-(cell,slot) loss contribution.
// pred slot layout: offset, dur, conf, cls0..cls2  (slot1 at +6 words)
// target slot layout: conf, cls, offset, dur       (slot1 at +4 words)
__device__ __forceinline__ float slot_loss(float pc, float l0, float l1, float l2,
                                           float po, float pd,
                                           float tc, float tcls, float to, float td,
                                           bool do_cls) {
    float d = tc - pc;
    bool obj = (tc == 1.0f);
    float w = obj ? 1.0f : ((tc == 0.0f) ? NOOBJ_SCALE : 0.0f);
    float r = w * d * d;

    if (obj) {
        float doff = to - po;
        r += COORD_SCALE * doff * doff;
        float dd = sqrtf(td) - sqrtf(pd);
        r += COORD_SCALE * dd * dd;
    }
    if (do_cls) {
        float x0, x1, x2;
        int idx;
        if (obj) { x0 = l0; x1 = l1; x2 = l2; idx = (int)tcls; }
        else     { x0 = 0.f; x1 = 0.f; x2 = 0.f; idx = 0; }
        float m = fmaxf(x0, fmaxf(x1, x2));
        float lse = logf(expf(x0 - m) + expf(x1 - m) + expf(x2 - m)) + m;
        float li = (idx == 0) ? x0 : ((idx == 1) ? x1 : x2);
        r += lse - li;   // cross-entropy = logsumexp - logit[target]
    }
    return r;
}

// No LDS staging: each cell is consumed by exactly ONE thread and its 48+32 B
// are thread-contiguous, so per-thread float4 loads give 100% byte efficiency
// (a wave's 5 loads cover contiguous 3KB+2KB windows; stride-48 holes in one
// instruction are covered by neighboring lanes via L1). This removes the LDS
// round-trip, the barrier, and ~40 instructions/thread vs the staged version.
__global__ __launch_bounds__(256) void ensemble_loss_kernel(
        const float* __restrict__ pred,
        const float* __restrict__ target,
        double* __restrict__ partials) {
    __shared__ float wsum[4];

    const int tid = threadIdx.x;
    const long long cell = (long long)blockIdx.x * TPB + tid;

    // pred words 0..11 for this cell (streaming, single-use -> nontemporal)
    const f4* __restrict__ pb = (const f4*)pred + cell * 3;
    f4 p0 = __builtin_nontemporal_load(pb + 0);   // w0..w3
    f4 p1 = __builtin_nontemporal_load(pb + 1);   // w4..w7
    f4 p2 = __builtin_nontemporal_load(pb + 2);   // w8..w11
    // target words 0..7
    const f4* __restrict__ tb = (const f4*)target + cell * 2;
    f4 t0 = __builtin_nontemporal_load(tb + 0);   // conf0, cls0, off0, dur0
    f4 t1 = __builtin_nontemporal_load(tb + 1);   // conf1, cls1, off1, dur1

    const bool do_cls = cell < CLS_CELLS;         // blocks 0..31 only (wave-uniform)

    float acc = 0.0f;
    // slot0: conf=w2, cls=w3,w4,w5, off=w0, dur=w1
    acc += slot_loss(p0.z, p0.w, p1.x, p1.y, p0.x, p0.y,
                     t0.x, t0.y, t0.z, t0.w, do_cls);
    // slot1: conf=w8, cls=w9,w10,w11, off=w6, dur=w7
    acc += slot_loss(p2.x, p2.y, p2.z, p2.w, p1.z, p1.w,
                     t1.x, t1.y, t1.z, t1.w, do_cls);

    // wave(64) shuffle reduction
    for (int off = 32; off > 0; off >>= 1)
        acc += __shfl_down(acc, off, 64);

    const int lane = tid & 63;
    const int wv = tid >> 6;
    if (lane == 0) wsum[wv] = acc;
    __syncthreads();
    if (tid == 0) {
        float s = wsum[0] + wsum[1] + wsum[2] + wsum[3];
        // Private slot per block, written unconditionally -> poison-safe, no memset.
        partials[blockIdx.x] = (double)s;
    }
}

__global__ __launch_bounds__(256) void finalize_kernel(
        const double* __restrict__ partials,
        float* __restrict__ out) {
    __shared__ double wsum[4];
    const int tid = threadIdx.x;

    // 16384 doubles = 128 KB; thread t reads slots t, t+256, ... (coalesced).
    double s = 0.0;
    #pragma unroll
    for (int i = 0; i < NBLOCKS / TPB; ++i)
        s += partials[i * TPB + tid];

    for (int off = 32; off > 0; off >>= 1)
        s += __shfl_down(s, off, 64);

    int lane = tid & 63;
    int wv = tid >> 6;
    if (lane == 0) wsum[wv] = s;
    __syncthreads();
    if (tid == 0) {
        double t = wsum[0] + wsum[1] + wsum[2] + wsum[3];
        out[0] = (float)(t * (1.0 / (double)B_SZ));
    }
}

extern "C" void kernel_launch(void* const* d_in, const int* in_sizes, int n_in,
                              void* d_out, int out_size, void* d_ws, size_t ws_size,
                              hipStream_t stream) {
    const float* pred   = (const float*)d_in[0];
    const float* target = (const float*)d_in[1];
    float* out = (float*)d_out;
    double* partials = (double*)d_ws;

    // Two dispatches, no memset (all partial slots written unconditionally,
    // so per-launch 0xAA ws poison is harmless).
    ensemble_loss_kernel<<<NBLOCKS, TPB, 0, stream>>>(pred, target, partials);
    finalize_kernel<<<1, TPB, 0, stream>>>(partials, out);
}

// Round 4
// 335.519 us; speedup vs baseline: 3.0191x; 1.0146x over previous
//
#include <hip/hip_runtime.h>
#include <math.h>

// Problem constants (from reference)
constexpr int B_SZ = 16384;
constexpr long long CELLS = 4194304;   // 16384*256 cells, 2 anchor slots each
constexpr int CLS_CELLS = 8192;        // logits[:batch_size] -> first 8192 cells get cls loss
constexpr float NOOBJ_SCALE = 0.5f;
constexpr float COORD_SCALE = 5.0f;

constexpr int TPB = 256;               // threads per block == cells per block
constexpr int PRED_PITCH = 13;         // 12 floats + 1 pad (odd stride -> 2-way LDS = free)
constexpr int TGT_PITCH  = 9;          // 8 floats + 1 pad
constexpr int NBLOCKS = (int)(CELLS / TPB);   // 16384 partial slots in d_ws (128 KB)

// 0xAA byte poison as a 64-bit pattern. As a double this is a NEGATIVE value
// (~ -3.7e-103); partials are sums of non-negative loss terms, so a computed
// partial can never equal it -> the partial's own bits serve as the "ready" flag.
constexpr unsigned long long POISON64 = 0xAAAAAAAAAAAAAAAAULL;

// Native clang vector so __builtin_nontemporal_load is applicable.
typedef float f4 __attribute__((ext_vector_type(4)));

// Per-(cell,slot) loss contribution.
// pred slot layout: offset=p0, dur=p1, conf=p2, cls=p3..p5  (slot1: +6)
// target slot layout: conf, cls, offset, dur                (slot1: +4)
__device__ __forceinline__ float slot_loss(float pc, float l0, float l1, float l2,
                                           float po, float pd,
                                           float tc, float tcls, float to, float td,
                                           bool do_cls) {
    float d = tc - pc;
    bool obj = (tc == 1.0f);
    float w = obj ? 1.0f : ((tc == 0.0f) ? NOOBJ_SCALE : 0.0f);
    float r = w * d * d;

    if (obj) {
        float doff = to - po;
        r += COORD_SCALE * doff * doff;
        float dd = sqrtf(td) - sqrtf(pd);
        r += COORD_SCALE * dd * dd;
    }
    if (do_cls) {
        float x0, x1, x2;
        int idx;
        if (obj) { x0 = l0; x1 = l1; x2 = l2; idx = (int)tcls; }
        else     { x0 = 0.f; x1 = 0.f; x2 = 0.f; idx = 0; }
        float m = fmaxf(x0, fmaxf(x1, x2));
        float lse = logf(expf(x0 - m) + expf(x1 - m) + expf(x2 - m)) + m;
        float li = (idx == 0) ? x0 : ((idx == 1) ? x1 : x2);
        r += lse - li;   // cross-entropy = logsumexp - logit[target]
    }
    return r;
}

// Round-1 proven structure (LDS-staged, lane-contiguous loads) + fenceless
// fused finalize. Each block's partial goes out as an agent-scope RELAXED
// 8-byte atomic store (single-copy atomic, cache-bypassing, NO fence — round
// 2's regression was the per-block RELEASE fence forcing 16384 L2 writebacks).
// The last-dispatched block spins until each slot's bit pattern != poison and
// consumes the loaded value directly: data-as-flag needs no ordering.
__global__ __launch_bounds__(256) void ensemble_loss_kernel(
        const float* __restrict__ pred,
        const float* __restrict__ target,
        unsigned long long* __restrict__ partials,
        float* __restrict__ out) {
    // Padded LDS tiles: 256*13*4 = 13312 B + 256*9*4 = 9216 B = ~22.5 KB
    __shared__ float spred[TPB * PRED_PITCH];
    __shared__ float star[TPB * TGT_PITCH];
    __shared__ float wsumf[4];
    __shared__ double wsumd[4];

    const int tid = threadIdx.x;
    const long long cell0 = (long long)blockIdx.x * TPB;

    // ---- stage pred: 768 float4/block, lane-contiguous (coalesced) ----
    // float4 #g covers words 4g..4g+3; 3 float4 per cell, never straddles.
    const f4* __restrict__ pbase = (const f4*)pred + cell0 * 3;
    #pragma unroll
    for (int r = 0; r < 3; ++r) {
        int g = r * TPB + tid;              // 0..767
        f4 v = __builtin_nontemporal_load(pbase + g);
        int cell = g / 3;                   // magic-mul div
        int sub  = g - cell * 3;
        int a = cell * PRED_PITCH + 4 * sub;
        spred[a + 0] = v.x; spred[a + 1] = v.y;
        spred[a + 2] = v.z; spred[a + 3] = v.w;
    }
    // ---- stage target: 512 float4/block, lane-contiguous ----
    const f4* __restrict__ tbase = (const f4*)target + cell0 * 2;
    #pragma unroll
    for (int r = 0; r < 2; ++r) {
        int g = r * TPB + tid;              // 0..511
        f4 v = __builtin_nontemporal_load(tbase + g);
        int cell = g >> 1;
        int sub  = g & 1;
        int a = cell * TGT_PITCH + 4 * sub;
        star[a + 0] = v.x; star[a + 1] = v.y;
        star[a + 2] = v.z; star[a + 3] = v.w;
    }
    __syncthreads();

    // ---- compute: thread t handles cell (cell0 + t); padded stride reads
    //      are 2 lanes/bank (free) ----
    const float* P = &spred[tid * PRED_PITCH];
    const float* T = &star[tid * TGT_PITCH];
    const bool do_cls = (cell0 + tid) < CLS_CELLS;   // blocks 0..31 only (wave-uniform)

    float acc = 0.0f;
    acc += slot_loss(P[2], P[3], P[4], P[5], P[0], P[1],
                     T[0], T[1], T[2], T[3], do_cls);
    acc += slot_loss(P[8], P[9], P[10], P[11], P[6], P[7],
                     T[4], T[5], T[6], T[7], do_cls);

    // wave(64) shuffle reduction
    for (int off = 32; off > 0; off >>= 1)
        acc += __shfl_down(acc, off, 64);

    const int lane = tid & 63;
    const int wv = tid >> 6;
    if (lane == 0) wsumf[wv] = acc;
    __syncthreads();
    if (tid == 0) {
        float s = wsumf[0] + wsumf[1] + wsumf[2] + wsumf[3];
        // Relaxed agent-scope 8B atomic store: coherent across XCDs, no fence.
        // (Partial >= 0 always, so its bits can never equal the 0xAA poison.)
        __hip_atomic_store(&partials[blockIdx.x],
                           __builtin_bit_cast(unsigned long long, (double)s),
                           __ATOMIC_RELAXED, __HIP_MEMORY_SCOPE_AGENT);
    }

    if (blockIdx.x != NBLOCKS - 1) return;

    // ---- fused finalize (last-dispatched block; in-order CP => near-zero spin).
    // Thread t owns slots t, t+256, ... (coalesced). Same summation order as
    // the old finalize kernel -> bit-identical output.
    double s = 0.0;
    for (int i = 0; i < NBLOCKS / TPB; ++i) {
        unsigned long long raw;
        for (;;) {
            raw = __hip_atomic_load(&partials[i * TPB + tid],
                                    __ATOMIC_RELAXED, __HIP_MEMORY_SCOPE_AGENT);
            if (raw != POISON64) break;
            __builtin_amdgcn_s_sleep(4);   // backoff; slot not yet written
        }
        s += __builtin_bit_cast(double, raw);
    }

    for (int off = 32; off > 0; off >>= 1)
        s += __shfl_down(s, off, 64);

    if (lane == 0) wsumd[wv] = s;
    __syncthreads();
    if (tid == 0) {
        double t = wsumd[0] + wsumd[1] + wsumd[2] + wsumd[3];
        out[0] = (float)(t * (1.0 / (double)B_SZ));
    }
}

extern "C" void kernel_launch(void* const* d_in, const int* in_sizes, int n_in,
                              void* d_out, int out_size, void* d_ws, size_t ws_size,
                              hipStream_t stream) {
    const float* pred   = (const float*)d_in[0];
    const float* target = (const float*)d_in[1];
    float* out = (float*)d_out;
    unsigned long long* partials = (unsigned long long*)d_ws;

    // Single dispatch, no memset: every partial slot is written unconditionally,
    // and the 0xAA poison doubles as the not-yet-ready flag (data-as-flag).
    ensemble_loss_kernel<<<NBLOCKS, TPB, 0, stream>>>(pred, target, partials, out);
}

// Round 5
// 323.410 us; speedup vs baseline: 3.1321x; 1.0374x over previous
//
#include <hip/hip_runtime.h>
#include <math.h>

// Problem constants (from reference)
constexpr int B_SZ = 16384;
constexpr long long CELLS = 4194304;   // 16384*256 cells, 2 anchor slots each
constexpr int CLS_CELLS = 8192;        // logits[:batch_size] -> first 8192 cells get cls loss
constexpr float NOOBJ_SCALE = 0.5f;
constexpr float COORD_SCALE = 5.0f;

constexpr int TPB = 256;               // threads per block == cells per block
constexpr int PRED_PITCH = 13;         // 12 floats + 1 pad (odd stride -> 2-way LDS = free)
constexpr int TGT_PITCH  = 9;          // 8 floats + 1 pad
constexpr int NBLOCKS = (int)(CELLS / TPB);   // 16384 partial slots in d_ws (128 KB)

// Native clang vector so __builtin_nontemporal_load is applicable (float4 is a struct).
typedef float f4 __attribute__((ext_vector_type(4)));

// Per-(cell,slot) loss contribution.
// pred slot layout: offset=p0, dur=p1, conf=p2, cls=p3..p5  (slot1: +6)
// target slot layout: conf, cls, offset, dur                (slot1: +4)
__device__ __forceinline__ float slot_loss(float pc, float l0, float l1, float l2,
                                           float po, float pd,
                                           float tc, float tcls, float to, float td,
                                           bool do_cls) {
    float d = tc - pc;
    bool obj = (tc == 1.0f);
    float w = obj ? 1.0f : ((tc == 0.0f) ? NOOBJ_SCALE : 0.0f);
    float r = w * d * d;

    if (obj) {
        float doff = to - po;
        r += COORD_SCALE * doff * doff;
        float dd = sqrtf(td) - sqrtf(pd);
        r += COORD_SCALE * dd * dd;
    }
    if (do_cls) {
        float x0, x1, x2;
        int idx;
        if (obj) { x0 = l0; x1 = l1; x2 = l2; idx = (int)tcls; }
        else     { x0 = 0.f; x1 = 0.f; x2 = 0.f; idx = 0; }
        float m = fmaxf(x0, fmaxf(x1, x2));
        float lse = logf(expf(x0 - m) + expf(x1 - m) + expf(x2 - m)) + m;
        float li = (idx == 0) ? x0 : ((idx == 1) ? x1 : x2);
        r += lse - li;   // cross-entropy = logsumexp - logit[target]
    }
    return r;
}

// Best-measured structure (324.2 us). Session findings baked in as comments:
//  - LDS staging with lane-contiguous float4 loads BEATS direct per-thread
//    stride-48 loads (+16 us tested): per-instruction line count matters more
//    than L1 reuse across instructions.
//  - A separate 256-thread finalize dispatch BEATS fused in-kernel completion:
//    release-fence version costs an L2 writeback per block (+689 us); even the
//    fenceless data-as-flag version loses (+11 us) to uncached poll traffic.
//  - No memset needed: every partial slot is written unconditionally each
//    launch, so the harness's 0xAA workspace poison is harmless.
__global__ __launch_bounds__(256) void ensemble_loss_kernel(
        const float* __restrict__ pred,
        const float* __restrict__ target,
        double* __restrict__ partials) {
    // Padded LDS tiles: 256*13*4 = 13312 B + 256*9*4 = 9216 B = ~22.5 KB
    __shared__ float spred[TPB * PRED_PITCH];
    __shared__ float star[TPB * TGT_PITCH];
    __shared__ float wsum[4];

    const int tid = threadIdx.x;
    const long long cell0 = (long long)blockIdx.x * TPB;

    // ---- stage pred: 768 float4/block, lane-contiguous (coalesced) ----
    // float4 #g covers words 4g..4g+3; 3 float4 per cell, never straddles.
    // Streaming single-use data: nontemporal (no reuse; poison fill evicts caches anyway).
    const f4* __restrict__ pbase = (const f4*)pred + cell0 * 3;
    #pragma unroll
    for (int r = 0; r < 3; ++r) {
        int g = r * TPB + tid;              // 0..767
        f4 v = __builtin_nontemporal_load(pbase + g);
        int cell = g / 3;                   // magic-mul div
        int sub  = g - cell * 3;
        int a = cell * PRED_PITCH + 4 * sub;
        spred[a + 0] = v.x; spred[a + 1] = v.y;
        spred[a + 2] = v.z; spred[a + 3] = v.w;
    }
    // ---- stage target: 512 float4/block, lane-contiguous ----
    const f4* __restrict__ tbase = (const f4*)target + cell0 * 2;
    #pragma unroll
    for (int r = 0; r < 2; ++r) {
        int g = r * TPB + tid;              // 0..511
        f4 v = __builtin_nontemporal_load(tbase + g);
        int cell = g >> 1;
        int sub  = g & 1;
        int a = cell * TGT_PITCH + 4 * sub;
        star[a + 0] = v.x; star[a + 1] = v.y;
        star[a + 2] = v.z; star[a + 3] = v.w;
    }
    __syncthreads();

    // ---- compute: thread t handles cell (cell0 + t); padded stride reads
    //      are 2 lanes/bank (free) ----
    const float* P = &spred[tid * PRED_PITCH];
    const float* T = &star[tid * TGT_PITCH];
    const bool do_cls = (cell0 + tid) < CLS_CELLS;   // blocks 0..31 only (wave-uniform)

    float acc = 0.0f;
    acc += slot_loss(P[2], P[3], P[4], P[5], P[0], P[1],
                     T[0], T[1], T[2], T[3], do_cls);
    acc += slot_loss(P[8], P[9], P[10], P[11], P[6], P[7],
                     T[4], T[5], T[6], T[7], do_cls);

    // wave(64) shuffle reduction
    for (int off = 32; off > 0; off >>= 1)
        acc += __shfl_down(acc, off, 64);

    int lane = tid & 63;
    int wv = tid >> 6;
    if (lane == 0) wsum[wv] = acc;
    __syncthreads();
    if (tid == 0) {
        float s = wsum[0] + wsum[1] + wsum[2] + wsum[3];
        // Private slot per block: written unconditionally every launch -> poison-safe.
        partials[blockIdx.x] = (double)s;
    }
}

__global__ __launch_bounds__(256) void finalize_kernel(
        const double* __restrict__ partials,
        float* __restrict__ out) {
    __shared__ double wsum[4];
    const int tid = threadIdx.x;

    // 16384 doubles = 128 KB; thread t reads slots t, t+256, ... (coalesced).
    double s = 0.0;
    #pragma unroll
    for (int i = 0; i < NBLOCKS / TPB; ++i)
        s += partials[i * TPB + tid];

    for (int off = 32; off > 0; off >>= 1)
        s += __shfl_down(s, off, 64);

    int lane = tid & 63;
    int wv = tid >> 6;
    if (lane == 0) wsum[wv] = s;
    __syncthreads();
    if (tid == 0) {
        double t = wsum[0] + wsum[1] + wsum[2] + wsum[3];
        out[0] = (float)(t * (1.0 / (double)B_SZ));
    }
}

extern "C" void kernel_launch(void* const* d_in, const int* in_sizes, int n_in,
                              void* d_out, int out_size, void* d_ws, size_t ws_size,
                              hipStream_t stream) {
    const float* pred   = (const float*)d_in[0];
    const float* target = (const float*)d_in[1];
    float* out = (float*)d_out;
    double* partials = (double*)d_ws;

    // Two dispatches, no memset.
    ensemble_loss_kernel<<<NBLOCKS, TPB, 0, stream>>>(pred, target, partials);
    finalize_kernel<<<1, TPB, 0, stream>>>(partials, out);
}